// Round 5
// baseline (159.744 us; speedup 1.0000x reference)
//
#include <hip/hip_runtime.h>

// NonLocalBlock (SAGAN non-local) fused pipeline for MI355X / gfx950.
// B=8, Cin=256, H=W=64 (HW=4096), Cout=512. All GEMMs via fp16 MFMA
// (16x16x32, fp32 accum). Workspace layout (~46 MB of d_ws):
//   [0,16MB)   xT   fp16 [8][4096][256]   (x transposed, n-major)
//   [16,20MB)  Q    fp16 [8][4096][64]    (theta proj, n-major)
//   [20,21MB)  Kp   fp16 [8][1024][64]
//   [21,25MB)  V    fp16 [8][256][1024]
//   [25MB+0)   Wproj fp16 [384][256]  (theta|phi|g, pre-scaled)
//   [25MB+512K) Wcat fp16 [512][512]
//   [26,46MB)  F    fp16 [8][320][4096] full-res phi|g proj; att aliases here
//
// R4->R5: R4's 4-wave/98KB-LDS config left 1 wave/SIMD (Occupancy 11%) ->
// pure latency stall (MfmaUtil 8%). Now 512 threads = 8 waves (2/SIMD),
// QBLK=128, waves = 4 row-groups x 2 channel-groups: each wave does 32 rows
// (V-frag regs reused across two 16-row halves, R4 trick) x 128 channels
// (V-frag LDS reads halved again). QK^T+softmax duplicated across the
// channel pair (cheap) so waves stay independent; P wave-private; K/V
// double-buffered; one barrier/kt. LDS 116KB -> 1 block/CU x 8 waves.

typedef _Float16 f16;
typedef f16 f16x8 __attribute__((ext_vector_type(8)));
typedef float f32x4 __attribute__((ext_vector_type(4)));

#define MFMA16(a, b, c) __builtin_amdgcn_mfma_f32_16x16x32_f16((a), (b), (c), 0, 0, 0)

__device__ __forceinline__ void gload16(const void* src, void* dst_lds) {
  __builtin_amdgcn_global_load_lds(
      (const __attribute__((address_space(1))) void*)src,
      (__attribute__((address_space(3))) void*)dst_lds, 16, 0, 0);
}

// -------------------------------------------------------------------------
__global__ __launch_bounds__(256, 4)
void k_prep_w(const float* __restrict__ wt, const float* __restrict__ wp,
              const float* __restrict__ wg, const float* __restrict__ wo,
              const float* __restrict__ wr, const float* __restrict__ gamma,
              f16* __restrict__ Wproj, f16* __restrict__ Wcat) {
  int i = blockIdx.x * 256 + threadIdx.x;
  const float s = 0.08838834764831845f;    // sqrt(2/256)
  const float is2 = 0.7071067811865476f;   // 1/sqrt(2)
  if (i < 384 * 256) {
    float v = (i < 64 * 256) ? wt[i]
              : (i < 128 * 256 ? wp[i - 64 * 256] : wg[i - 128 * 256]);
    Wproj[i] = (f16)(v * s);
  } else {
    int j = i - 384 * 256;
    if (j < 512 * 512) {
      int r = j >> 9, c = j & 511;
      float v = (c < 256) ? wo[r * 256 + c] * (gamma[0] * s * is2)
                          : wr[r * 256 + (c - 256)] * (s * is2);
      Wcat[j] = (f16)v;
    }
  }
}

// -------------------------------------------------------------------------
// Transpose x [b][256][4096] fp32 -> xT [b][4096][256] fp16 via 64x64 LDS tiles.
__global__ __launch_bounds__(256, 4)
void k_transpose(const float* __restrict__ x, f16* __restrict__ xT) {
  __shared__ f16 tile[64 * 72];
  int b = blockIdx.z, nt = blockIdx.y, ct = blockIdx.x;
  int t = threadIdx.x;
  {
    int c = t >> 2, nch = (t & 3) * 16;
    const float* src = x + (((size_t)b * 256 + ct * 64 + c) << 12) + nt * 64 + nch;
    float4 v0 = *(const float4*)(src);
    float4 v1 = *(const float4*)(src + 4);
    float4 v2 = *(const float4*)(src + 8);
    float4 v3 = *(const float4*)(src + 12);
    f16x8 a = {(f16)v0.x, (f16)v0.y, (f16)v0.z, (f16)v0.w,
               (f16)v1.x, (f16)v1.y, (f16)v1.z, (f16)v1.w};
    f16x8 bb = {(f16)v2.x, (f16)v2.y, (f16)v2.z, (f16)v2.w,
                (f16)v3.x, (f16)v3.y, (f16)v3.z, (f16)v3.w};
    *(f16x8*)&tile[c * 72 + nch] = a;
    *(f16x8*)&tile[c * 72 + nch + 8] = bb;
  }
  __syncthreads();
  {
    int n = t >> 2, cch = (t & 3) * 16;
    f16 tmp[16];
#pragma unroll
    for (int i = 0; i < 16; i++) tmp[i] = tile[(cch + i) * 72 + n];
    f16x8 a, bb;
#pragma unroll
    for (int i = 0; i < 8; i++) { a[i] = tmp[i]; bb[i] = tmp[8 + i]; }
    f16* dst = xT + (((size_t)b * 4096 + nt * 64 + n) << 8) + ct * 64 + cch;
    *(f16x8*)dst = a;
    *(f16x8*)(dst + 8) = bb;
  }
}

// -------------------------------------------------------------------------
// Merged projection GEMM: out rows = Wproj rows [mt*64, mt*64+64).
// mt==0 -> theta -> Q[b][n][64]; mt>=1 -> phi|g -> F[b][jj][n].
__global__ __launch_bounds__(256, 2)
void k_gemm_projq(const f16* __restrict__ xT, const f16* __restrict__ Wproj,
                  f16* __restrict__ Q, f16* __restrict__ F) {
  __shared__ f16 Alds[64 * 64];
  __shared__ f16 Blds[128 * 64];
  int b = blockIdx.z, mt = blockIdx.y, nt = blockIdx.x;
  int lane = threadIdx.x & 63, wave = threadIdx.x >> 6;
  int wm = wave >> 1, wn = wave & 1;
  f32x4 acc[2][4];
#pragma unroll
  for (int mf = 0; mf < 2; mf++)
#pragma unroll
    for (int nf = 0; nf < 4; nf++) acc[mf][nf] = (f32x4){0, 0, 0, 0};
  const f16* Abase = Wproj + ((mt * 64) << 8);
  const f16* Bbase = xT + (((size_t)b * 4096 + nt * 128) << 8);
  for (int k0 = 0; k0 < 256; k0 += 64) {
    __syncthreads();
#pragma unroll
    for (int i = 0; i < 2; i++) {
      int chunk = i * 256 + threadIdx.x;
      int row = chunk >> 3, cc = chunk & 7, scc = cc ^ (row & 7);
      gload16(Abase + (row << 8) + k0 + scc * 8, (char*)Alds + (i * 256 + wave * 64) * 16);
    }
#pragma unroll
    for (int i = 0; i < 4; i++) {
      int chunk = i * 256 + threadIdx.x;
      int row = chunk >> 3, cc = chunk & 7, scc = cc ^ (row & 7);
      gload16(Bbase + (row << 8) + k0 + scc * 8, (char*)Blds + (i * 256 + wave * 64) * 16);
    }
    __syncthreads();
#pragma unroll
    for (int ks = 0; ks < 2; ks++) {
      int cb = ((lane >> 4) * 8 + ks * 32) * 2;
      f16x8 af[2], bf[4];
#pragma unroll
      for (int mf = 0; mf < 2; mf++) {
        int row = wm * 32 + mf * 16 + (lane & 15);
        af[mf] = *(const f16x8*)((const char*)Alds + row * 128 + (cb ^ ((row & 7) << 4)));
      }
#pragma unroll
      for (int nf = 0; nf < 4; nf++) {
        int row = wn * 64 + nf * 16 + (lane & 15);
        bf[nf] = *(const f16x8*)((const char*)Blds + row * 128 + (cb ^ ((row & 7) << 4)));
      }
#pragma unroll
      for (int mf = 0; mf < 2; mf++)
#pragma unroll
        for (int nf = 0; nf < 4; nf++) acc[mf][nf] = MFMA16(af[mf], bf[nf], acc[mf][nf]);
    }
  }
#pragma unroll
  for (int mf = 0; mf < 2; mf++)
#pragma unroll
    for (int nf = 0; nf < 4; nf++)
#pragma unroll
      for (int r = 0; r < 4; r++) {
        int jl = wm * 32 + mf * 16 + (lane >> 4) * 4 + r;  // 0..63
        int n = nt * 128 + wn * 64 + nf * 16 + (lane & 15);
        f16 v = (f16)acc[mf][nf][r];
        if (mt == 0)
          Q[(((size_t)b * 4096 + n) << 6) + jl] = v;
        else
          F[(((size_t)b * 320 + (mt - 1) * 64 + jl) << 12) + n] = v;
      }
}

// -------------------------------------------------------------------------
// 2x2 maxpool: F[b][jj][4096] -> jj<64: Kp[b][m][jj] (phi), jj>=64: V[b][jj-64][m].
__global__ __launch_bounds__(256, 4)
void k_pool(const f16* __restrict__ F, f16* __restrict__ Kp, f16* __restrict__ V) {
  int id = blockIdx.x * 256 + threadIdx.x;  // < 8*320*32 = 81920
  int ph = id & 31;
  int rest = id >> 5;
  int jj = rest % 320;
  int b = rest / 320;
  const f16x8* r0 = (const f16x8*)(F + (((size_t)b * 320 + jj) << 12) + ph * 128);
  const f16x8* r1 = r0 + 8;
  f16 outv[32];
#pragma unroll
  for (int ch = 0; ch < 8; ch++) {
    f16x8 u = r0[ch], v = r1[ch];
#pragma unroll
    for (int p = 0; p < 4; p++) {
      float m1 = fmaxf(fmaxf((float)u[2 * p], (float)u[2 * p + 1]),
                       fmaxf((float)v[2 * p], (float)v[2 * p + 1]));
      outv[ch * 4 + p] = (f16)m1;
    }
  }
  int m0 = ph * 32;
  if (jj < 64) {
#pragma unroll
    for (int p = 0; p < 32; p++)
      Kp[((size_t)b * 1024 + m0 + p) * 64 + jj] = outv[p];
  } else {
    f16* dst = V + (((size_t)b * 256 + (jj - 64)) << 10) + m0;
#pragma unroll
    for (int c8 = 0; c8 < 4; c8++) {
      f16x8 w;
#pragma unroll
      for (int i = 0; i < 8; i++) w[i] = outv[c8 * 8 + i];
      *(f16x8*)(dst + c8 * 8) = w;
    }
  }
}

// -------------------------------------------------------------------------
// Flash attention: Q [4096][64], K [1024][64], V [256][1024] -> att [n][c].
// 512 threads = 8 waves = 4 row-groups x 2 channel-groups. Each wave: 32 Q-rows
// (2 halves of 16, V/K frag regs shared across halves) x 128 V-channels.
// K/V double-buffered in LDS; QK^T+softmax duplicated across channel pair.
__global__ __launch_bounds__(512, 1)
void k_flash(const f16* __restrict__ Q, const f16* __restrict__ Kp,
             const f16* __restrict__ V, f16* __restrict__ att) {
  __shared__ f16 Klds[2][64 * 64];    // [m][c] swizzled, 8KB each
  __shared__ f16 Vlds[2][256 * 64];   // [c][m] swizzled, 32KB each
  __shared__ f16 Plds[8][32 * 72];    // per-wave P [q][m], padded
  int b = blockIdx.y, qt = blockIdx.x;
  int tid = threadIdx.x;
  int lane = tid & 63, wave = tid >> 6;   // 8 waves
  int rg = wave >> 1, cg2 = wave & 1;     // row-group 0..3, channel-group 0..1
  int l15 = lane & 15, hi = lane >> 4;
  const f16* Kb = Kp + ((size_t)b << 16);
  const f16* Vb = V + ((size_t)b << 18);
  f16* Pw = &Plds[wave][0];
  // Q fragments: rows qt*128 + rg*32 + h*16 + l15
  f16x8 qf[2][2];
#pragma unroll
  for (int h = 0; h < 2; h++)
#pragma unroll
    for (int ks = 0; ks < 2; ks++)
      qf[h][ks] = *(const f16x8*)(
          Q + (((size_t)b * 4096 + qt * 128 + rg * 32 + h * 16 + l15) << 6) +
          ks * 32 + hi * 8);
  f32x4 o[2][8];
#pragma unroll
  for (int h = 0; h < 2; h++)
#pragma unroll
    for (int i = 0; i < 8; i++) o[h][i] = (f32x4){0, 0, 0, 0};
  float mrow[2][4], lrow[2][4];
#pragma unroll
  for (int h = 0; h < 2; h++)
#pragma unroll
    for (int r = 0; r < 4; r++) { mrow[h][r] = -1e30f; lrow[h][r] = 0.f; }

  int cbase = hi * 16;  // byte offset of this lane's 16B k-chunk within a 128B row

#define STAGE(bufi, kt)                                                          \
  {                                                                              \
    {                                                                            \
      int chunk = tid;                                                           \
      int row = chunk >> 3, cc = chunk & 7, scc = cc ^ (row & 7);                \
      gload16(Kb + (((kt) * 64 + row) << 6) + scc * 8,                           \
              (char*)&Klds[bufi][0] + chunk * 16);                               \
    }                                                                            \
    _Pragma("unroll") for (int i = 0; i < 4; i++) {                              \
      int chunk = i * 512 + tid;                                                 \
      int row = chunk >> 3, cc = chunk & 7, scc = cc ^ (row & 7);                \
      gload16(Vb + ((size_t)row << 10) + (kt) * 64 + scc * 8,                    \
              (char*)&Vlds[bufi][0] + chunk * 16);                               \
    }                                                                            \
  }

  STAGE(0, 0);
  __syncthreads();
  int buf = 0;
  for (int kt = 0; kt < 16; ++kt) {
    if (kt < 15) STAGE(buf ^ 1, kt + 1);
    // ---- S = Q K^T (K-frags shared across both q-halves; dup across cg2)
    f32x4 s[2][4];
#pragma unroll
    for (int h = 0; h < 2; h++)
#pragma unroll
      for (int mf = 0; mf < 4; mf++) s[h][mf] = (f32x4){0, 0, 0, 0};
#pragma unroll
    for (int ks = 0; ks < 2; ks++) {
      f16x8 kf[4];
#pragma unroll
      for (int mf = 0; mf < 4; mf++) {
        int row = mf * 16 + l15;
        kf[mf] = *(const f16x8*)((const char*)&Klds[buf][0] + row * 128 +
                                 ((cbase + ks * 64) ^ ((row & 7) << 4)));
      }
#pragma unroll
      for (int h = 0; h < 2; h++)
#pragma unroll
        for (int mf = 0; mf < 4; mf++)
          s[h][mf] = MFMA16(qf[h][ks], kf[mf], s[h][mf]);
    }
    // ---- online softmax (defer-max, THR=8)
    float pmax[2][4];
#pragma unroll
    for (int h = 0; h < 2; h++)
#pragma unroll
      for (int r = 0; r < 4; r++) {
        float v = fmaxf(fmaxf(s[h][0][r], s[h][1][r]), fmaxf(s[h][2][r], s[h][3][r]));
        v = fmaxf(v, __shfl_xor(v, 1));
        v = fmaxf(v, __shfl_xor(v, 2));
        v = fmaxf(v, __shfl_xor(v, 4));
        v = fmaxf(v, __shfl_xor(v, 8));
        pmax[h][r] = v;
      }
    bool need = false;
#pragma unroll
    for (int h = 0; h < 2; h++)
#pragma unroll
      for (int r = 0; r < 4; r++) need |= (pmax[h][r] > mrow[h][r] + 8.f);
    if (__any(need)) {
#pragma unroll
      for (int h = 0; h < 2; h++)
#pragma unroll
        for (int r = 0; r < 4; r++) {
          float mnew = fmaxf(mrow[h][r], pmax[h][r]);
          float corr = exp2f((mrow[h][r] - mnew) * 1.44269504f);
          lrow[h][r] *= corr;
          mrow[h][r] = mnew;
#pragma unroll
          for (int cf = 0; cf < 8; cf++) o[h][cf][r] *= corr;
        }
    }
#pragma unroll
    for (int h = 0; h < 2; h++) {
      int prow = hi * 4;
#pragma unroll
      for (int r = 0; r < 4; r++) {
        float sum = 0.f;
        float e[4];
#pragma unroll
        for (int mf = 0; mf < 4; mf++) {
          e[mf] = exp2f((s[h][mf][r] - mrow[h][r]) * 1.44269504f);
          sum += e[mf];
        }
#pragma unroll
        for (int mf = 0; mf < 4; mf++)
          Pw[(h * 16 + prow + r) * 72 + mf * 16 + l15] = (f16)e[mf];
        sum += __shfl_xor(sum, 1);
        sum += __shfl_xor(sum, 2);
        sum += __shfl_xor(sum, 4);
        sum += __shfl_xor(sum, 8);
        lrow[h][r] += sum;
      }
    }
    // ---- PV: this wave covers channels cg2*128 .. cg2*128+127
#pragma unroll
    for (int ks = 0; ks < 2; ks++) {
      f16x8 af[2];
#pragma unroll
      for (int h = 0; h < 2; h++)
        af[h] = *(const f16x8*)(Pw + (h * 16 + l15) * 72 + ks * 32 + hi * 8);
      __builtin_amdgcn_s_setprio(1);
#pragma unroll
      for (int cg = 0; cg < 2; cg++) {
        f16x8 vf[4];
#pragma unroll
        for (int u = 0; u < 4; u++) {
          int row = (cg2 * 8 + cg * 4 + u) * 16 + l15;
          vf[u] = *(const f16x8*)((const char*)&Vlds[buf][0] + row * 128 +
                                  ((cbase + ks * 64) ^ ((row & 7) << 4)));
        }
#pragma unroll
        for (int h = 0; h < 2; h++)
#pragma unroll
          for (int u = 0; u < 4; u++)
            o[h][cg * 4 + u] = MFMA16(af[h], vf[u], o[h][cg * 4 + u]);
      }
      __builtin_amdgcn_s_setprio(0);
    }
    __syncthreads();
    buf ^= 1;
  }
#undef STAGE
  int nbase = qt * 128 + rg * 32 + hi * 4;
#pragma unroll
  for (int h = 0; h < 2; h++)
#pragma unroll
    for (int r = 0; r < 4; r++) {
      float inv = 1.f / lrow[h][r];
#pragma unroll
      for (int cf = 0; cf < 8; cf++) {
        int n = nbase + h * 16 + r;
        int c = cg2 * 128 + cf * 16 + l15;
        att[(((size_t)b * 4096 + n) << 8) + c] = (f16)(o[h][cf][r] * inv);
      }
    }
}

// -------------------------------------------------------------------------
// Output GEMM: out[b][o][n] = sum_{k<512} Wcat[o][k] * Bcat[n][k], Bcat=[att|xT].
__global__ __launch_bounds__(256, 2)
void k_gemm_out(const f16* __restrict__ Wcat, const f16* __restrict__ att,
                const f16* __restrict__ xT, float* __restrict__ out) {
  __shared__ f16 Alds[128 * 64];
  __shared__ f16 Blds[128 * 64];
  int b = blockIdx.z, mt = blockIdx.y, nt = blockIdx.x;
  int lane = threadIdx.x & 63, wave = threadIdx.x >> 6;
  int wm = wave >> 1, wn = wave & 1;
  f32x4 acc[4][4];
#pragma unroll
  for (int mf = 0; mf < 4; mf++)
#pragma unroll
    for (int nf = 0; nf < 4; nf++) acc[mf][nf] = (f32x4){0, 0, 0, 0};
  const f16* Abase = Wcat + (size_t)(mt * 128) * 512;
  for (int k0 = 0; k0 < 512; k0 += 64) {
    __syncthreads();
#pragma unroll
    for (int i = 0; i < 4; i++) {
      int chunk = i * 256 + threadIdx.x;
      int row = chunk >> 3, cc = chunk & 7, scc = cc ^ (row & 7);
      gload16(Abase + row * 512 + k0 + scc * 8, (char*)Alds + (i * 256 + wave * 64) * 16);
    }
    const f16* Bcol = (k0 < 256) ? (att + (((size_t)b * 4096 + nt * 128) << 8))
                                 : (xT + (((size_t)b * 4096 + nt * 128) << 8));
    int kk = (k0 < 256) ? k0 : (k0 - 256);
#pragma unroll
    for (int i = 0; i < 4; i++) {
      int chunk = i * 256 + threadIdx.x;
      int row = chunk >> 3, cc = chunk & 7, scc = cc ^ (row & 7);
      gload16(Bcol + (row << 8) + kk + scc * 8, (char*)Blds + (i * 256 + wave * 64) * 16);
    }
    __syncthreads();
#pragma unroll
    for (int ks = 0; ks < 2; ks++) {
      int cb = ((lane >> 4) * 8 + ks * 32) * 2;
      f16x8 af[4], bf[4];
#pragma unroll
      for (int mf = 0; mf < 4; mf++) {
        int row = wm * 64 + mf * 16 + (lane & 15);
        af[mf] = *(const f16x8*)((const char*)Alds + row * 128 + (cb ^ ((row & 7) << 4)));
      }
#pragma unroll
      for (int nf = 0; nf < 4; nf++) {
        int row = wn * 64 + nf * 16 + (lane & 15);
        bf[nf] = *(const f16x8*)((const char*)Blds + row * 128 + (cb ^ ((row & 7) << 4)));
      }
#pragma unroll
      for (int mf = 0; mf < 4; mf++)
#pragma unroll
        for (int nf = 0; nf < 4; nf++) acc[mf][nf] = MFMA16(af[mf], bf[nf], acc[mf][nf]);
    }
  }
#pragma unroll
  for (int mf = 0; mf < 4; mf++)
#pragma unroll
    for (int nf = 0; nf < 4; nf++)
#pragma unroll
      for (int r = 0; r < 4; r++) {
        int oo = mt * 128 + wm * 64 + mf * 16 + (lane >> 4) * 4 + r;
        int n = nt * 128 + wn * 64 + nf * 16 + (lane & 15);
        out[(((size_t)b * 512 + oo) << 12) + n] = acc[mf][nf][r];
      }
}

// -------------------------------------------------------------------------
extern "C" void kernel_launch(void* const* d_in, const int* in_sizes, int n_in,
                              void* d_out, int out_size, void* d_ws, size_t ws_size,
                              hipStream_t stream) {
  const float* x = (const float*)d_in[0];
  const float* wt = (const float*)d_in[1];
  const float* wp = (const float*)d_in[2];
  const float* wg = (const float*)d_in[3];
  const float* wo = (const float*)d_in[4];
  const float* wr = (const float*)d_in[5];
  const float* gm = (const float*)d_in[6];
  float* out = (float*)d_out;
  char* ws = (char*)d_ws;
  const size_t MB = 1024 * 1024;
  f16* xT = (f16*)(ws);
  f16* Qb = (f16*)(ws + 16 * MB);
  f16* Kp = (f16*)(ws + 20 * MB);
  f16* Vb = (f16*)(ws + 21 * MB);
  f16* Wproj = (f16*)(ws + 25 * MB);
  f16* Wcat = (f16*)(ws + 25 * MB + 512 * 1024);
  f16* F = (f16*)(ws + 26 * MB);
  f16* att = F;  // alias: F fully consumed by k_pool before k_flash writes att

  hipLaunchKernelGGL(k_prep_w, dim3(1408), dim3(256), 0, stream, wt, wp, wg, wo, wr, gm,
                     Wproj, Wcat);
  hipLaunchKernelGGL(k_transpose, dim3(4, 64, 8), dim3(256), 0, stream, x, xT);
  hipLaunchKernelGGL(k_gemm_projq, dim3(32, 6, 8), dim3(256), 0, stream, xT, Wproj, Qb, F);
  hipLaunchKernelGGL(k_pool, dim3(320), dim3(256), 0, stream, F, Kp, Vb);
  hipLaunchKernelGGL(k_flash, dim3(32, 8), dim3(512), 0, stream, Qb, Kp, Vb, att);
  hipLaunchKernelGGL(k_gemm_out, dim3(32, 4, 8), dim3(256), 0, stream, Wcat, att, xT, out);
}

// Round 6
// 135.957 us; speedup vs baseline: 1.1750x; 1.1750x over previous
//
#include <hip/hip_runtime.h>

// NonLocalBlock (SAGAN non-local) fused pipeline for MI355X / gfx950.
// B=8, Cin=256, H=W=64 (HW=4096), Cout=512. All GEMMs via fp16 MFMA
// (16x16x32, fp32 accum). Workspace layout (~46 MB of d_ws):
//   [0,16MB)   xT   fp16 [8][4096][256]   (x transposed, n-major)
//   [16,20MB)  Q    fp16 [8][4096][64]    (theta proj, n-major)
//   [20,21MB)  Kp   fp16 [8][1024][64]
//   [21,25MB)  V    fp16 [8][256][1024]
//   [25MB+0)   Wproj fp16 [384][256]  (theta|phi|g, pre-scaled)
//   [25MB+512K) Wcat fp16 [512][512]
//   [26,46MB)  F    fp16 [8][320][4096] full-res phi|g proj; att aliases here
//
// R5->R6: R5's flash was LDS-PIPE-bound: 64 shfl (ds_bpermute) + 32 scalar
// P-writes per wave per kt ~= 124 LDS ops (MfmaUtil 11%, bankconf 524K).
// Swapped QK^T: s = MFMA(kf, qf) puts a full q-row's 16 scores lane-local ->
// softmax = in-lane trees + 2 shfls; P stored as packed f16x4 b64 writes
// (8/kt) read back as 4 b128 frags. ~44 LDS ops/wave/kt. m/l per-lane;
// o-row rescale/normalize factors fetched by rare shfls.

typedef _Float16 f16;
typedef f16 f16x4 __attribute__((ext_vector_type(4)));
typedef f16 f16x8 __attribute__((ext_vector_type(8)));
typedef float f32x4 __attribute__((ext_vector_type(4)));

#define MFMA16(a, b, c) __builtin_amdgcn_mfma_f32_16x16x32_f16((a), (b), (c), 0, 0, 0)

__device__ __forceinline__ void gload16(const void* src, void* dst_lds) {
  __builtin_amdgcn_global_load_lds(
      (const __attribute__((address_space(1))) void*)src,
      (__attribute__((address_space(3))) void*)dst_lds, 16, 0, 0);
}

// -------------------------------------------------------------------------
__global__ __launch_bounds__(256, 4)
void k_prep_w(const float* __restrict__ wt, const float* __restrict__ wp,
              const float* __restrict__ wg, const float* __restrict__ wo,
              const float* __restrict__ wr, const float* __restrict__ gamma,
              f16* __restrict__ Wproj, f16* __restrict__ Wcat) {
  int i = blockIdx.x * 256 + threadIdx.x;
  const float s = 0.08838834764831845f;    // sqrt(2/256)
  const float is2 = 0.7071067811865476f;   // 1/sqrt(2)
  if (i < 384 * 256) {
    float v = (i < 64 * 256) ? wt[i]
              : (i < 128 * 256 ? wp[i - 64 * 256] : wg[i - 128 * 256]);
    Wproj[i] = (f16)(v * s);
  } else {
    int j = i - 384 * 256;
    if (j < 512 * 512) {
      int r = j >> 9, c = j & 511;
      float v = (c < 256) ? wo[r * 256 + c] * (gamma[0] * s * is2)
                          : wr[r * 256 + (c - 256)] * (s * is2);
      Wcat[j] = (f16)v;
    }
  }
}

// -------------------------------------------------------------------------
// Transpose x [b][256][4096] fp32 -> xT [b][4096][256] fp16 via 64x64 LDS tiles.
__global__ __launch_bounds__(256, 4)
void k_transpose(const float* __restrict__ x, f16* __restrict__ xT) {
  __shared__ f16 tile[64 * 72];
  int b = blockIdx.z, nt = blockIdx.y, ct = blockIdx.x;
  int t = threadIdx.x;
  {
    int c = t >> 2, nch = (t & 3) * 16;
    const float* src = x + (((size_t)b * 256 + ct * 64 + c) << 12) + nt * 64 + nch;
    float4 v0 = *(const float4*)(src);
    float4 v1 = *(const float4*)(src + 4);
    float4 v2 = *(const float4*)(src + 8);
    float4 v3 = *(const float4*)(src + 12);
    f16x8 a = {(f16)v0.x, (f16)v0.y, (f16)v0.z, (f16)v0.w,
               (f16)v1.x, (f16)v1.y, (f16)v1.z, (f16)v1.w};
    f16x8 bb = {(f16)v2.x, (f16)v2.y, (f16)v2.z, (f16)v2.w,
                (f16)v3.x, (f16)v3.y, (f16)v3.z, (f16)v3.w};
    *(f16x8*)&tile[c * 72 + nch] = a;
    *(f16x8*)&tile[c * 72 + nch + 8] = bb;
  }
  __syncthreads();
  {
    int n = t >> 2, cch = (t & 3) * 16;
    f16 tmp[16];
#pragma unroll
    for (int i = 0; i < 16; i++) tmp[i] = tile[(cch + i) * 72 + n];
    f16x8 a, bb;
#pragma unroll
    for (int i = 0; i < 8; i++) { a[i] = tmp[i]; bb[i] = tmp[8 + i]; }
    f16* dst = xT + (((size_t)b * 4096 + nt * 64 + n) << 8) + ct * 64 + cch;
    *(f16x8*)dst = a;
    *(f16x8*)(dst + 8) = bb;
  }
}

// -------------------------------------------------------------------------
// Merged projection GEMM: out rows = Wproj rows [mt*64, mt*64+64).
// mt==0 -> theta -> Q[b][n][64]; mt>=1 -> phi|g -> F[b][jj][n].
__global__ __launch_bounds__(256, 2)
void k_gemm_projq(const f16* __restrict__ xT, const f16* __restrict__ Wproj,
                  f16* __restrict__ Q, f16* __restrict__ F) {
  __shared__ f16 Alds[64 * 64];
  __shared__ f16 Blds[128 * 64];
  int b = blockIdx.z, mt = blockIdx.y, nt = blockIdx.x;
  int lane = threadIdx.x & 63, wave = threadIdx.x >> 6;
  int wm = wave >> 1, wn = wave & 1;
  f32x4 acc[2][4];
#pragma unroll
  for (int mf = 0; mf < 2; mf++)
#pragma unroll
    for (int nf = 0; nf < 4; nf++) acc[mf][nf] = (f32x4){0, 0, 0, 0};
  const f16* Abase = Wproj + ((mt * 64) << 8);
  const f16* Bbase = xT + (((size_t)b * 4096 + nt * 128) << 8);
  for (int k0 = 0; k0 < 256; k0 += 64) {
    __syncthreads();
#pragma unroll
    for (int i = 0; i < 2; i++) {
      int chunk = i * 256 + threadIdx.x;
      int row = chunk >> 3, cc = chunk & 7, scc = cc ^ (row & 7);
      gload16(Abase + (row << 8) + k0 + scc * 8, (char*)Alds + (i * 256 + wave * 64) * 16);
    }
#pragma unroll
    for (int i = 0; i < 4; i++) {
      int chunk = i * 256 + threadIdx.x;
      int row = chunk >> 3, cc = chunk & 7, scc = cc ^ (row & 7);
      gload16(Bbase + (row << 8) + k0 + scc * 8, (char*)Blds + (i * 256 + wave * 64) * 16);
    }
    __syncthreads();
#pragma unroll
    for (int ks = 0; ks < 2; ks++) {
      int cb = ((lane >> 4) * 8 + ks * 32) * 2;
      f16x8 af[2], bf[4];
#pragma unroll
      for (int mf = 0; mf < 2; mf++) {
        int row = wm * 32 + mf * 16 + (lane & 15);
        af[mf] = *(const f16x8*)((const char*)Alds + row * 128 + (cb ^ ((row & 7) << 4)));
      }
#pragma unroll
      for (int nf = 0; nf < 4; nf++) {
        int row = wn * 64 + nf * 16 + (lane & 15);
        bf[nf] = *(const f16x8*)((const char*)Blds + row * 128 + (cb ^ ((row & 7) << 4)));
      }
#pragma unroll
      for (int mf = 0; mf < 2; mf++)
#pragma unroll
        for (int nf = 0; nf < 4; nf++) acc[mf][nf] = MFMA16(af[mf], bf[nf], acc[mf][nf]);
    }
  }
#pragma unroll
  for (int mf = 0; mf < 2; mf++)
#pragma unroll
    for (int nf = 0; nf < 4; nf++)
#pragma unroll
      for (int r = 0; r < 4; r++) {
        int jl = wm * 32 + mf * 16 + (lane >> 4) * 4 + r;  // 0..63
        int n = nt * 128 + wn * 64 + nf * 16 + (lane & 15);
        f16 v = (f16)acc[mf][nf][r];
        if (mt == 0)
          Q[(((size_t)b * 4096 + n) << 6) + jl] = v;
        else
          F[(((size_t)b * 320 + (mt - 1) * 64 + jl) << 12) + n] = v;
      }
}

// -------------------------------------------------------------------------
// 2x2 maxpool: F[b][jj][4096] -> jj<64: Kp[b][m][jj] (phi), jj>=64: V[b][jj-64][m].
__global__ __launch_bounds__(256, 4)
void k_pool(const f16* __restrict__ F, f16* __restrict__ Kp, f16* __restrict__ V) {
  int id = blockIdx.x * 256 + threadIdx.x;  // < 8*320*32 = 81920
  int ph = id & 31;
  int rest = id >> 5;
  int jj = rest % 320;
  int b = rest / 320;
  const f16x8* r0 = (const f16x8*)(F + (((size_t)b * 320 + jj) << 12) + ph * 128);
  const f16x8* r1 = r0 + 8;
  f16 outv[32];
#pragma unroll
  for (int ch = 0; ch < 8; ch++) {
    f16x8 u = r0[ch], v = r1[ch];
#pragma unroll
    for (int p = 0; p < 4; p++) {
      float m1 = fmaxf(fmaxf((float)u[2 * p], (float)u[2 * p + 1]),
                       fmaxf((float)v[2 * p], (float)v[2 * p + 1]));
      outv[ch * 4 + p] = (f16)m1;
    }
  }
  int m0 = ph * 32;
  if (jj < 64) {
#pragma unroll
    for (int p = 0; p < 32; p++)
      Kp[((size_t)b * 1024 + m0 + p) * 64 + jj] = outv[p];
  } else {
    f16* dst = V + (((size_t)b * 256 + (jj - 64)) << 10) + m0;
#pragma unroll
    for (int c8 = 0; c8 < 4; c8++) {
      f16x8 w;
#pragma unroll
      for (int i = 0; i < 8; i++) w[i] = outv[c8 * 8 + i];
      *(f16x8*)(dst + c8 * 8) = w;
    }
  }
}

// -------------------------------------------------------------------------
// Flash attention, swapped-QK^T: Q [4096][64], K [1024][64], V [256][1024]
// -> att [n][c]. 512 threads = 8 waves = 4 row-groups x 2 channel-groups.
// Each wave: 32 q-rows x 128 channels. s = MFMA(kf, qf): lane (hi,l15) holds
// q-row l15 (per h-half), keys mf*16+hi*4+r -> lane-local softmax.
__global__ __launch_bounds__(512, 2)
void k_flash(const f16* __restrict__ Q, const f16* __restrict__ Kp,
             const f16* __restrict__ V, f16* __restrict__ att) {
  __shared__ f16 Klds[2][64 * 64];    // [m][c] swizzled, 8KB each
  __shared__ f16 Vlds[2][256 * 64];   // [c][m] swizzled, 32KB each
  __shared__ f16 Plds[8][32 * 72];    // per-wave P [q][key], 144B rows
  int b = blockIdx.y, qt = blockIdx.x;
  int tid = threadIdx.x;
  int lane = tid & 63, wave = tid >> 6;   // 8 waves
  int rg = wave >> 1, cg2 = wave & 1;     // row-group 0..3, channel-group 0..1
  int l15 = lane & 15, hi = lane >> 4;
  const f16* Kb = Kp + ((size_t)b << 16);
  const f16* Vb = V + ((size_t)b << 18);
  f16* Pw = &Plds[wave][0];
  const float L2E = 1.44269504f;
  // Q fragments: rows qt*128 + rg*32 + h*16 + l15
  f16x8 qf[2][2];
#pragma unroll
  for (int h = 0; h < 2; h++)
#pragma unroll
    for (int ks = 0; ks < 2; ks++)
      qf[h][ks] = *(const f16x8*)(
          Q + (((size_t)b * 4096 + qt * 128 + rg * 32 + h * 16 + l15) << 6) +
          ks * 32 + hi * 8);
  f32x4 o[2][8];
#pragma unroll
  for (int h = 0; h < 2; h++)
#pragma unroll
    for (int i = 0; i < 8; i++) o[h][i] = (f32x4){0, 0, 0, 0};
  float mrow[2] = {-1e30f, -1e30f};
  float lrow[2] = {0.f, 0.f};

  int cbase = hi * 16;  // byte offset of this lane's 16B k-chunk within a 128B row

#define STAGE(bufi, kt)                                                          \
  {                                                                              \
    {                                                                            \
      int chunk = tid;                                                           \
      int row = chunk >> 3, cc = chunk & 7, scc = cc ^ (row & 7);                \
      gload16(Kb + (((kt) * 64 + row) << 6) + scc * 8,                           \
              (char*)&Klds[bufi][0] + chunk * 16);                               \
    }                                                                            \
    _Pragma("unroll") for (int i = 0; i < 4; i++) {                              \
      int chunk = i * 512 + tid;                                                 \
      int row = chunk >> 3, cc = chunk & 7, scc = cc ^ (row & 7);                \
      gload16(Vb + ((size_t)row << 10) + (kt) * 64 + scc * 8,                    \
              (char*)&Vlds[bufi][0] + chunk * 16);                               \
    }                                                                            \
  }

  STAGE(0, 0);
  __syncthreads();
  int buf = 0;
  for (int kt = 0; kt < 16; ++kt) {
    if (kt < 15) STAGE(buf ^ 1, kt + 1);
    // ---- S^T = K Q^T: lane holds q-row l15 (h-half), keys mf*16+hi*4+r
    f32x4 s[2][4];
#pragma unroll
    for (int h = 0; h < 2; h++)
#pragma unroll
      for (int mf = 0; mf < 4; mf++) s[h][mf] = (f32x4){0, 0, 0, 0};
#pragma unroll
    for (int ks = 0; ks < 2; ks++) {
      f16x8 kf[4];
#pragma unroll
      for (int mf = 0; mf < 4; mf++) {
        int row = mf * 16 + l15;
        kf[mf] = *(const f16x8*)((const char*)&Klds[buf][0] + row * 128 +
                                 ((cbase + ks * 64) ^ ((row & 7) << 4)));
      }
#pragma unroll
      for (int h = 0; h < 2; h++)
#pragma unroll
        for (int mf = 0; mf < 4; mf++)
          s[h][mf] = MFMA16(kf[mf], qf[h][ks], s[h][mf]);
    }
    // ---- lane-local online softmax (defer-max THR=8)
    float pmax[2];
#pragma unroll
    for (int h = 0; h < 2; h++) {
      float t0 = fmaxf(fmaxf(s[h][0][0], s[h][1][0]), fmaxf(s[h][2][0], s[h][3][0]));
      float t1 = fmaxf(fmaxf(s[h][0][1], s[h][1][1]), fmaxf(s[h][2][1], s[h][3][1]));
      float t2 = fmaxf(fmaxf(s[h][0][2], s[h][1][2]), fmaxf(s[h][2][2], s[h][3][2]));
      float t3 = fmaxf(fmaxf(s[h][0][3], s[h][1][3]), fmaxf(s[h][2][3], s[h][3][3]));
      float mx = fmaxf(fmaxf(t0, t1), fmaxf(t2, t3));
      mx = fmaxf(mx, __shfl_xor(mx, 16, 64));
      mx = fmaxf(mx, __shfl_xor(mx, 32, 64));
      pmax[h] = mx;
    }
    bool need = (pmax[0] > mrow[0] + 8.f) || (pmax[1] > mrow[1] + 8.f);
    if (__any(need)) {
#pragma unroll
      for (int h = 0; h < 2; h++) {
        float mnew = fmaxf(mrow[h], pmax[h]);
        float corr = exp2f((mrow[h] - mnew) * L2E);
        lrow[h] *= corr;
        mrow[h] = mnew;
#pragma unroll
        for (int r = 0; r < 4; r++) {
          float cr = __shfl(corr, (hi << 4) + (hi << 2) + r, 64);
#pragma unroll
          for (int cf = 0; cf < 8; cf++) o[h][cf][r] *= cr;
        }
      }
    }
#pragma unroll
    for (int h = 0; h < 2; h++) {
      float e[4][4];
#pragma unroll
      for (int mf = 0; mf < 4; mf++)
#pragma unroll
        for (int r = 0; r < 4; r++)
          e[mf][r] = exp2f((s[h][mf][r] - mrow[h]) * L2E);
      // pack & store P row (key k = mf*16 + hi*4 + r at byte k*2)
#pragma unroll
      for (int mf = 0; mf < 4; mf++) {
        f16x4 w = {(f16)e[mf][0], (f16)e[mf][1], (f16)e[mf][2], (f16)e[mf][3]};
        *(f16x4*)((char*)Pw + (h * 16 + l15) * 144 + mf * 32 + hi * 8) = w;
      }
      float u0 = (e[0][0] + e[1][0]) + (e[2][0] + e[3][0]);
      float u1 = (e[0][1] + e[1][1]) + (e[2][1] + e[3][1]);
      float u2 = (e[0][2] + e[1][2]) + (e[2][2] + e[3][2]);
      float u3 = (e[0][3] + e[1][3]) + (e[2][3] + e[3][3]);
      float sum = (u0 + u1) + (u2 + u3);
      sum += __shfl_xor(sum, 16, 64);
      sum += __shfl_xor(sum, 32, 64);
      lrow[h] += sum;
    }
    // ---- PV: this wave covers channels cg2*128 .. cg2*128+127
#pragma unroll
    for (int ks = 0; ks < 2; ks++) {
      f16x8 af[2];
#pragma unroll
      for (int h = 0; h < 2; h++)
        af[h] = *(const f16x8*)((char*)Pw + (h * 16 + l15) * 144 + ks * 64 + hi * 16);
      __builtin_amdgcn_s_setprio(1);
#pragma unroll
      for (int cg = 0; cg < 2; cg++) {
        f16x8 vf[4];
#pragma unroll
        for (int u = 0; u < 4; u++) {
          int row = (cg2 * 8 + cg * 4 + u) * 16 + l15;
          vf[u] = *(const f16x8*)((const char*)&Vlds[buf][0] + row * 128 +
                                  ((cbase + ks * 64) ^ ((row & 7) << 4)));
        }
#pragma unroll
        for (int h = 0; h < 2; h++)
#pragma unroll
          for (int u = 0; u < 4; u++)
            o[h][cg * 4 + u] = MFMA16(af[h], vf[u], o[h][cg * 4 + u]);
      }
      __builtin_amdgcn_s_setprio(0);
    }
    __syncthreads();
    buf ^= 1;
  }
#undef STAGE
  int nbase = qt * 128 + rg * 32 + hi * 4;
#pragma unroll
  for (int h = 0; h < 2; h++) {
    float inv = 1.f / lrow[h];
#pragma unroll
    for (int r = 0; r < 4; r++) {
      float iv = __shfl(inv, (hi << 4) + (hi << 2) + r, 64);
#pragma unroll
      for (int cf = 0; cf < 8; cf++) {
        int n = nbase + h * 16 + r;
        int c = cg2 * 128 + cf * 16 + l15;
        att[(((size_t)b * 4096 + n) << 8) + c] = (f16)(o[h][cf][r] * iv);
      }
    }
  }
}

// -------------------------------------------------------------------------
// Output GEMM: out[b][o][n] = sum_{k<512} Wcat[o][k] * Bcat[n][k], Bcat=[att|xT].
__global__ __launch_bounds__(256, 2)
void k_gemm_out(const f16* __restrict__ Wcat, const f16* __restrict__ att,
                const f16* __restrict__ xT, float* __restrict__ out) {
  __shared__ f16 Alds[128 * 64];
  __shared__ f16 Blds[128 * 64];
  int b = blockIdx.z, mt = blockIdx.y, nt = blockIdx.x;
  int lane = threadIdx.x & 63, wave = threadIdx.x >> 6;
  int wm = wave >> 1, wn = wave & 1;
  f32x4 acc[4][4];
#pragma unroll
  for (int mf = 0; mf < 4; mf++)
#pragma unroll
    for (int nf = 0; nf < 4; nf++) acc[mf][nf] = (f32x4){0, 0, 0, 0};
  const f16* Abase = Wcat + (size_t)(mt * 128) * 512;
  for (int k0 = 0; k0 < 512; k0 += 64) {
    __syncthreads();
#pragma unroll
    for (int i = 0; i < 4; i++) {
      int chunk = i * 256 + threadIdx.x;
      int row = chunk >> 3, cc = chunk & 7, scc = cc ^ (row & 7);
      gload16(Abase + row * 512 + k0 + scc * 8, (char*)Alds + (i * 256 + wave * 64) * 16);
    }
    const f16* Bcol = (k0 < 256) ? (att + (((size_t)b * 4096 + nt * 128) << 8))
                                 : (xT + (((size_t)b * 4096 + nt * 128) << 8));
    int kk = (k0 < 256) ? k0 : (k0 - 256);
#pragma unroll
    for (int i = 0; i < 4; i++) {
      int chunk = i * 256 + threadIdx.x;
      int row = chunk >> 3, cc = chunk & 7, scc = cc ^ (row & 7);
      gload16(Bcol + (row << 8) + kk + scc * 8, (char*)Blds + (i * 256 + wave * 64) * 16);
    }
    __syncthreads();
#pragma unroll
    for (int ks = 0; ks < 2; ks++) {
      int cb = ((lane >> 4) * 8 + ks * 32) * 2;
      f16x8 af[4], bf[4];
#pragma unroll
      for (int mf = 0; mf < 4; mf++) {
        int row = wm * 64 + mf * 16 + (lane & 15);
        af[mf] = *(const f16x8*)((const char*)Alds + row * 128 + (cb ^ ((row & 7) << 4)));
      }
#pragma unroll
      for (int nf = 0; nf < 4; nf++) {
        int row = wn * 64 + nf * 16 + (lane & 15);
        bf[nf] = *(const f16x8*)((const char*)Blds + row * 128 + (cb ^ ((row & 7) << 4)));
      }
#pragma unroll
      for (int mf = 0; mf < 4; mf++)
#pragma unroll
        for (int nf = 0; nf < 4; nf++) acc[mf][nf] = MFMA16(af[mf], bf[nf], acc[mf][nf]);
    }
  }
#pragma unroll
  for (int mf = 0; mf < 4; mf++)
#pragma unroll
    for (int nf = 0; nf < 4; nf++)
#pragma unroll
      for (int r = 0; r < 4; r++) {
        int oo = mt * 128 + wm * 64 + mf * 16 + (lane >> 4) * 4 + r;
        int n = nt * 128 + wn * 64 + nf * 16 + (lane & 15);
        out[(((size_t)b * 512 + oo) << 12) + n] = acc[mf][nf][r];
      }
}

// -------------------------------------------------------------------------
extern "C" void kernel_launch(void* const* d_in, const int* in_sizes, int n_in,
                              void* d_out, int out_size, void* d_ws, size_t ws_size,
                              hipStream_t stream) {
  const float* x = (const float*)d_in[0];
  const float* wt = (const float*)d_in[1];
  const float* wp = (const float*)d_in[2];
  const float* wg = (const float*)d_in[3];
  const float* wo = (const float*)d_in[4];
  const float* wr = (const float*)d_in[5];
  const float* gm = (const float*)d_in[6];
  float* out = (float*)d_out;
  char* ws = (char*)d_ws;
  const size_t MB = 1024 * 1024;
  f16* xT = (f16*)(ws);
  f16* Qb = (f16*)(ws + 16 * MB);
  f16* Kp = (f16*)(ws + 20 * MB);
  f16* Vb = (f16*)(ws + 21 * MB);
  f16* Wproj = (f16*)(ws + 25 * MB);
  f16* Wcat = (f16*)(ws + 25 * MB + 512 * 1024);
  f16* F = (f16*)(ws + 26 * MB);
  f16* att = F;  // alias: F fully consumed by k_pool before k_flash writes att

  hipLaunchKernelGGL(k_prep_w, dim3(1408), dim3(256), 0, stream, wt, wp, wg, wo, wr, gm,
                     Wproj, Wcat);
  hipLaunchKernelGGL(k_transpose, dim3(4, 64, 8), dim3(256), 0, stream, x, xT);
  hipLaunchKernelGGL(k_gemm_projq, dim3(32, 6, 8), dim3(256), 0, stream, xT, Wproj, Qb, F);
  hipLaunchKernelGGL(k_pool, dim3(320), dim3(256), 0, stream, F, Kp, Vb);
  hipLaunchKernelGGL(k_flash, dim3(32, 8), dim3(512), 0, stream, Qb, Kp, Vb, att);
  hipLaunchKernelGGL(k_gemm_out, dim3(32, 4, 8), dim3(256), 0, stream, Wcat, att, xT, out);
}